// Round 11
// baseline (536.319 us; speedup 1.0000x reference)
//
#include <hip/hip_runtime.h>
#include <hip/hip_bf16.h>
#include <stdint.h>

typedef float f32x4 __attribute__((ext_vector_type(4)));
typedef __bf16 bf16x8 __attribute__((ext_vector_type(8)));
typedef unsigned short u16;

#define MFMA16(a, b, c) __builtin_amdgcn_mfma_f32_16x16x32_bf16((a), (b), (c), 0, 0, 0)

__device__ __forceinline__ u16 f2bf(float f) {
  union { float f; uint32_t u; } v; v.f = f;
  uint32_t u = v.u;
  return (u16)((u + 0x7fffu + ((u >> 16) & 1u)) >> 16);
}
__device__ __forceinline__ float bf2f(u16 h) {
  union { uint32_t u; float f; } v; v.u = ((uint32_t)h) << 16;
  return v.f;
}

// ---------------- kernel 0: weights -> bf16 transposed [c][k] -----------------
__global__ void prep_weights_kernel(const float* __restrict__ Wq, const float* __restrict__ Wk,
                                    const float* __restrict__ Wv, const float* __restrict__ Wp,
                                    u16* __restrict__ Wt) {
  int w = blockIdx.x;
  const float* W = (w == 0) ? Wq : (w == 1) ? Wk : (w == 2) ? Wv : Wp;
  int t = blockIdx.y * 256 + threadIdx.x;  // 0..16383
  int c = t >> 7, k = t & 127;
  Wt[(w * 128 + c) * 128 + k] = f2bf(W[k * 128 + c]);
}

// ---------------- kernel 1: QKV projection -----------------------------------
// Q is written PRE-SCALED by 1/sqrt(128) so attn skips the per-score multiply.
__global__ __launch_bounds__(512) void qkv_kernel(
    const float* __restrict__ x, const u16* __restrict__ Wt,
    const float* __restrict__ bq, const float* __restrict__ bk, const float* __restrict__ bv,
    u16* __restrict__ Qb, u16* __restrict__ Kb, u16* __restrict__ Vt) {
  __shared__ u16 x_lds[128][136];
  __shared__ u16 w_lds[128][136];
  const int tid = threadIdx.x;
  const int m0 = blockIdx.x * 128;
  {  // stage x tile (fp32 -> bf16), coalesced
    int row = tid >> 2, cp = (tid & 3) * 32;
    const float* src = x + (size_t)(m0 + row) * 128 + cp;
    u16* dst = &x_lds[row][cp];
#pragma unroll
    for (int j = 0; j < 8; ++j) {
      float4 f = *(const float4*)(src + j * 4);
      dst[j * 4 + 0] = f2bf(f.x); dst[j * 4 + 1] = f2bf(f.y);
      dst[j * 4 + 2] = f2bf(f.z); dst[j * 4 + 3] = f2bf(f.w);
    }
  }
  __syncthreads();
  const int l = tid & 63, wv = tid >> 6, l15 = l & 15, l4 = l >> 4;
  const int rb = wv * 16;
  bf16x8 af[4];
#pragma unroll
  for (int ks = 0; ks < 4; ++ks)
    af[ks] = *(const bf16x8*)&x_lds[rb + l15][ks * 32 + l4 * 8];

#pragma unroll 1
  for (int o = 0; o < 3; ++o) {
    __syncthreads();
    {  // stage weight o into LDS
      int row = tid >> 2, cp = (tid & 3) * 32;
      const u16* src = Wt + (size_t)(o * 128 + row) * 128 + cp;
      u16* dst = &w_lds[row][cp];
#pragma unroll
      for (int j = 0; j < 4; ++j)
        *(bf16x8*)(dst + j * 8) = *(const bf16x8*)(src + j * 8);
    }
    __syncthreads();
    f32x4 acc[8];
#pragma unroll
    for (int ct = 0; ct < 8; ++ct) acc[ct] = f32x4{0.f, 0.f, 0.f, 0.f};
#pragma unroll
    for (int ct = 0; ct < 8; ++ct)
#pragma unroll
      for (int ks = 0; ks < 4; ++ks) {
        bf16x8 bfr = *(const bf16x8*)&w_lds[ct * 16 + l15][ks * 32 + l4 * 8];
        acc[ct] = MFMA16(af[ks], bfr, acc[ct]);
      }
    const float* bptr = (o == 0) ? bq : (o == 1) ? bk : bv;
    float bias[8];
#pragma unroll
    for (int ct = 0; ct < 8; ++ct) bias[ct] = bptr[ct * 16 + l15];
    const float osc = (o == 0) ? 0.088388347648318447f : 1.0f;  // fold 1/sqrt(d) into Q
    __syncthreads();
    if (o < 2) {  // store rows [tt][d]
#pragma unroll
      for (int ct = 0; ct < 8; ++ct)
#pragma unroll
        for (int rg = 0; rg < 4; ++rg)
          w_lds[rb + 4 * l4 + rg][ct * 16 + l15] = f2bf((acc[ct][rg] + bias[ct]) * osc);
    } else {      // V: store transposed [d][tt]
#pragma unroll
      for (int ct = 0; ct < 8; ++ct)
#pragma unroll
        for (int rg = 0; rg < 4; ++rg)
          w_lds[ct * 16 + l15][rb + 4 * l4 + rg] = f2bf(acc[ct][rg] + bias[ct]);
    }
    __syncthreads();
    {  // coalesced copy-out
      int row = tid >> 2, cp = (tid & 3) * 32;
      u16* dst;
      if (o == 0)      dst = Qb + (size_t)(m0 + row) * 128 + cp;
      else if (o == 1) dst = Kb + (size_t)(m0 + row) * 128 + cp;
      else {
        int n = m0 >> 8, tb = m0 & 255;
        dst = Vt + ((size_t)(n * 128 + row)) * 256 + tb + cp;
      }
      const u16* src = &w_lds[row][cp];
#pragma unroll
      for (int j = 0; j < 4; ++j)
        *(bf16x8*)(dst + j * 8) = *(const bf16x8*)(src + j * 8);
    }
  }
}

// ---------------- kernel 2: per-n mean of V ----------------------------------
__global__ void vmean_kernel(const u16* __restrict__ Vt, float* __restrict__ Vmean) {
  int n = blockIdx.x, d = threadIdx.x;
  const u16* row = Vt + ((size_t)(n * 128 + d)) * 256;
  float s = 0.f;
#pragma unroll 4
  for (int j = 0; j < 32; ++j) {
    uint4 u = *(const uint4*)(row + j * 8);
    uint32_t w0 = u.x, w1 = u.y, w2 = u.z, w3 = u.w;
    s += bf2f((u16)(w0 & 0xffff)) + bf2f((u16)(w0 >> 16));
    s += bf2f((u16)(w1 & 0xffff)) + bf2f((u16)(w1 >> 16));
    s += bf2f((u16)(w2 & 0xffff)) + bf2f((u16)(w2 >> 16));
    s += bf2f((u16)(w3 & 0xffff)) + bf2f((u16)(w3 >> 16));
  }
  Vmean[n * 128 + d] = s * (1.f / 256.f);
}

// ---- kernel 3 helpers: one 64-key tile's QK / softmax / PV phases -----------
__device__ __forceinline__ void qk16(const u16 K[][136], int s0, int l15, int l4,
                                     const bf16x8* qa, f32x4* sacc) {
#pragma unroll
  for (int ct = 0; ct < 4; ++ct) sacc[ct] = f32x4{0.f, 0.f, 0.f, 0.f};
#pragma unroll
  for (int ct = 0; ct < 4; ++ct)
#pragma unroll
    for (int ks = 0; ks < 4; ++ks) {
      bf16x8 bfr = *(const bf16x8*)&K[s0 + ct * 16 + l15][ks * 32 + l4 * 8];
      sacc[ct] = MFMA16(qa[ks], bfr, sacc[ct]);
    }
}

__device__ __forceinline__ void softmax16(const f32x4* sacc, int s0, int l15,
                                          const int* ttg, const int* qm,
                                          const int* __restrict__ mrow,
                                          const float* rel_lds,
                                          float* lsum, float p[4][4]) {
  int km[4];
#pragma unroll
  for (int ct = 0; ct < 4; ++ct) km[ct] = mrow[s0 + ct * 16 + l15];
#pragma unroll
  for (int ct = 0; ct < 4; ++ct) {
    const int ss = s0 + ct * 16 + l15;
#pragma unroll
    for (int rg = 0; rg < 4; ++rg) {
      float sv = sacc[ct][rg] + rel_lds[ttg[rg] - ss + 255];  // idx provably in [0,510]
      bool msk = (ss > ttg[rg]) | (km[ct] == 0) | (qm[rg] == 0);
      sv = msk ? -1.0e9f : sv;
      float pv = __expf(sv);            // masked -> 0 exactly (fixed-max softmax)
      p[ct][rg] = pv;
      lsum[rg] += pv;
    }
  }
}

__device__ __forceinline__ void pv16(const float p[4][4], int s0,
                                     const u16 V[][264], u16 Ps[16][40],
                                     int l15, int l4, f32x4* cacc) {
#pragma unroll
  for (int c = 0; c < 2; ++c) {
#pragma unroll
    for (int c2 = 0; c2 < 2; ++c2)
#pragma unroll
      for (int rg = 0; rg < 4; ++rg)
        Ps[4 * l4 + rg][c2 * 16 + l15] = f2bf(p[2 * c + c2][rg]);
    bf16x8 pa = *(const bf16x8*)&Ps[l15][l4 * 8];
#pragma unroll
    for (int ct = 0; ct < 8; ++ct) {
      bf16x8 vb = *(const bf16x8*)&V[ct * 16 + l15][s0 + c * 32 + l4 * 8];
      cacc[ct] = MFMA16(pa, vb, cacc[ct]);
    }
  }
}

// ---- kernel 3: block-per-n, fixed-max softmax, PAIR-BATCHED kv tiles --------
__global__ __launch_bounds__(1024, 4) void attn7_kernel(
    const u16* __restrict__ Qb, const u16* __restrict__ Kb, const u16* __restrict__ Vt,
    const u16* __restrict__ Wpt,
    const float* __restrict__ x, const int* __restrict__ mask,
    const float* __restrict__ rel, const float* __restrict__ bp,
    const float* __restrict__ ln_g, const float* __restrict__ ln_b,
    const float* __restrict__ Vmean, float* __restrict__ out) {
  __shared__ u16 K_lds[256][136];       // 69632 B
  __shared__ u16 V_lds[128][264];       // 67584 B  (V^T: [d][s])
  __shared__ u16 P_lds[16][16][40];     // 20480 B  per-wave P / ctx repack slices
  __shared__ float rel_lds[511];        //  2044 B  -> total 159740 B
  const int tid = threadIdx.x;
  const int n = blockIdx.x;
  const int bb = n / 100, rr = n - bb * 100;
  const int* mrow = mask + bb * 256;
  if (tid < 511) rel_lds[tid] = rel[tid];
  {  // stage K [256][128] -> K_lds
    int row = tid >> 2, cp = (tid & 3) * 32;
    const u16* src = Kb + ((size_t)(n * 256 + row)) * 128 + cp;
    u16* dst = &K_lds[row][cp];
#pragma unroll
    for (int j = 0; j < 4; ++j) *(bf16x8*)(dst + j * 8) = *(const bf16x8*)(src + j * 8);
  }
  {  // stage V^T [128][256] -> V_lds
    int row = tid >> 3, cq = (tid & 7) * 32;
    const u16* src = Vt + ((size_t)(n * 128 + row)) * 256 + cq;
    u16* dst = &V_lds[row][cq];
#pragma unroll
    for (int j = 0; j < 4; ++j) *(bf16x8*)(dst + j * 8) = *(const bf16x8*)(src + j * 8);
  }
  const int l = tid & 63, wv = tid >> 6, l15 = l & 15, l4 = l >> 4;
  const int tt0 = wv * 16;               // this wave's 16 q-rows
  bf16x8 qa[4];
  {
    const u16* qrow = Qb + ((size_t)(n * 256 + tt0 + l15)) * 128;
#pragma unroll
    for (int ks = 0; ks < 4; ++ks)
      qa[ks] = *(const bf16x8*)(qrow + ks * 32 + l4 * 8);
  }
  int ttg[4], qm[4];
#pragma unroll
  for (int rg = 0; rg < 4; ++rg) { ttg[rg] = tt0 + 4 * l4 + rg; qm[rg] = mrow[ttg[rg]]; }
  float lsum[4]; f32x4 cacc[8];
#pragma unroll
  for (int rg = 0; rg < 4; ++rg) lsum[rg] = 0.f;
#pragma unroll
  for (int ct = 0; ct < 8; ++ct) cacc[ct] = f32x4{0.f, 0.f, 0.f, 0.f};
  __syncthreads();  // staging complete; no more block syncs

  const int nkv = (wv >> 2) + 1;  // causal tiles for rows < 16*(wv+1)
  int kv = 0;
#pragma unroll 1
  for (; kv + 1 < nkv; kv += 2) {
    const int s0a = kv * 64, s0b = s0a + 64;
    f32x4 sa[4], sb[4];
    qk16(K_lds, s0a, l15, l4, qa, sa);
    qk16(K_lds, s0b, l15, l4, qa, sb);
    float pA[4][4];
    softmax16(sa, s0a, l15, ttg, qm, mrow, rel_lds, lsum, pA);
    pv16(pA, s0a, V_lds, P_lds[wv], l15, l4, cacc);
    float pB[4][4];
    softmax16(sb, s0b, l15, ttg, qm, mrow, rel_lds, lsum, pB);
    pv16(pB, s0b, V_lds, P_lds[wv], l15, l4, cacc);
  }
  if (kv < nkv) {
    const int s0 = kv * 64;
    f32x4 sa[4];
    qk16(K_lds, s0, l15, l4, qa, sa);
    float pA[4][4];
    softmax16(sa, s0, l15, ttg, qm, mrow, rel_lds, lsum, pA);
    pv16(pA, s0, V_lds, P_lds[wv], l15, l4, cacc);
  }
  float li[4];
#pragma unroll
  for (int rg = 0; rg < 4; ++rg) {
    float rs = lsum[rg];
#pragma unroll
    for (int off = 1; off < 16; off <<= 1) rs += __shfl_xor(rs, off);
    li[rg] = rs;
  }
  float vm[8];
#pragma unroll
  for (int ct = 0; ct < 8; ++ct) vm[ct] = Vmean[n * 128 + ct * 16 + l15];
  bf16x8 ca[4];
#pragma unroll
  for (int q = 0; q < 4; ++q) {
#pragma unroll
    for (int c2 = 0; c2 < 2; ++c2) {
      int ct = 2 * q + c2;
#pragma unroll
      for (int rg = 0; rg < 4; ++rg) {
        float cval = cacc[ct][rg] / li[rg];
        cval = (qm[rg] == 0) ? vm[ct] : cval;
        P_lds[wv][4 * l4 + rg][c2 * 16 + l15] = f2bf(cval);
      }
    }
    ca[q] = *(const bf16x8*)&P_lds[wv][l15][l4 * 8];
  }
  f32x4 oacc[8];
#pragma unroll
  for (int ct = 0; ct < 8; ++ct) oacc[ct] = f32x4{0.f, 0.f, 0.f, 0.f};
#pragma unroll
  for (int ct = 0; ct < 8; ++ct)
#pragma unroll
    for (int ks = 0; ks < 4; ++ks) {
      bf16x8 b = *(const bf16x8*)(Wpt + (size_t)(ct * 16 + l15) * 128 + ks * 32 + l4 * 8);
      oacc[ct] = MFMA16(ca[ks], b, oacc[ct]);
    }
  float bpv[8], gv[8], bt[8];
#pragma unroll
  for (int ct = 0; ct < 8; ++ct) {
    int d = ct * 16 + l15;
    bpv[ct] = bp[d]; gv[ct] = ln_g[d]; bt[ct] = ln_b[d];
  }
#pragma unroll
  for (int rg = 0; rg < 4; ++rg) {
    const int tg = ttg[rg];
    const float* xrow = x + ((size_t)(n * 256 + tg)) * 128;
    float yv[8], sum = 0.f, sq = 0.f;
#pragma unroll
    for (int ct = 0; ct < 8; ++ct) {
      float v = oacc[ct][rg] + bpv[ct] + xrow[ct * 16 + l15];
      yv[ct] = v; sum += v; sq += v * v;
    }
#pragma unroll
    for (int off = 1; off < 16; off <<= 1) { sum += __shfl_xor(sum, off); sq += __shfl_xor(sq, off); }
    float mean = sum * (1.f / 128.f);
    float var = sq * (1.f / 128.f) - mean * mean;
    float rstd = rsqrtf(var + 1e-5f);
    float* orow = out + (((size_t)(bb * 256 + tg)) * 100 + rr) * 128;
#pragma unroll
    for (int ct = 0; ct < 8; ++ct)
      orow[ct * 16 + l15] = (yv[ct] - mean) * rstd * gv[ct] + bt[ct];
  }
}

// ---- ABLATION probes, REPEATED so they clear the top-5 visibility cutoff ----
// VAR 0, REP 8: staging+Q-load only, CYCLING n each rep (streams a different
//   137 KB per rep -> doubles as an L3-bandwidth probe for our exact pattern).
//   >=150us -> flow-bound ~2TB/s; 80-150 -> staging-latency; invisible -> S<5us.
// VAR 2, REP 2: full compute, per-thread sink, no out-scatter.
//   W(scatter) = attn7 - ABL2/2; invisible -> scatter > 32us.
// Sinks live in the Qb region (fully rewritten by qkv each launch -> replay-safe).
template <int VAR, int REP>
__global__ __launch_bounds__(1024, 4) void attn_abl_kernel(
    const u16* __restrict__ Qb, const u16* __restrict__ Kb, const u16* __restrict__ Vt,
    const u16* __restrict__ Wpt,
    const float* __restrict__ x, const int* __restrict__ mask,
    const float* __restrict__ rel, const float* __restrict__ bp,
    const float* __restrict__ ln_g, const float* __restrict__ ln_b,
    const float* __restrict__ Vmean, float* __restrict__ sink) {
  __shared__ u16 K_lds[256][136];
  __shared__ u16 V_lds[128][264];
  __shared__ u16 P_lds[16][16][40];
  __shared__ float rel_lds[511];
  const int tid = threadIdx.x;
  if (tid < 511) rel_lds[tid] = rel[tid];
  const int l = tid & 63, wv = tid >> 6, l15 = l & 15, l4 = l >> 4;
  const int tt0 = wv * 16;
  float snk = 0.f;
#pragma unroll 1
  for (int rep = 0; rep < REP; ++rep) {
    int nn = blockIdx.x + ((VAR == 0) ? rep * 50 : 0);
    if (nn >= 400) nn -= 400;
    const int bb = nn / 100;
    const int* mrow = mask + bb * 256;
    __syncthreads();  // previous rep's readers done before re-staging
    {
      int row = tid >> 2, cp = (tid & 3) * 32;
      const u16* src = Kb + ((size_t)(nn * 256 + row)) * 128 + cp;
      u16* dst = &K_lds[row][cp];
#pragma unroll
      for (int j = 0; j < 4; ++j) *(bf16x8*)(dst + j * 8) = *(const bf16x8*)(src + j * 8);
    }
    {
      int row = tid >> 3, cq = (tid & 7) * 32;
      const u16* src = Vt + ((size_t)(nn * 128 + row)) * 256 + cq;
      u16* dst = &V_lds[row][cq];
#pragma unroll
      for (int j = 0; j < 4; ++j) *(bf16x8*)(dst + j * 8) = *(const bf16x8*)(src + j * 8);
    }
    bf16x8 qa[4];
    {
      const u16* qrow = Qb + ((size_t)(nn * 256 + tt0 + l15)) * 128;
#pragma unroll
      for (int ks = 0; ks < 4; ++ks)
        qa[ks] = *(const bf16x8*)(qrow + ks * 32 + l4 * 8);
    }
    int ttg[4], qm[4];
#pragma unroll
    for (int rg = 0; rg < 4; ++rg) { ttg[rg] = tt0 + 4 * l4 + rg; qm[rg] = mrow[ttg[rg]]; }
    __syncthreads();

    if (VAR == 0) {  // keep staging + Q live; no compute
#pragma unroll
      for (int ks = 0; ks < 4; ++ks) snk += (float)qa[ks][0];
      snk += bf2f(K_lds[(l * 5) & 255][(tid * 9) & 135]);
      snk += bf2f(V_lds[(l * 3) & 127][(tid * 17) & 263]);
      snk += (float)(qm[0] + ttg[0]);
      continue;
    }
    float lsum[4]; f32x4 cacc[8];
#pragma unroll
    for (int rg = 0; rg < 4; ++rg) lsum[rg] = 0.f;
#pragma unroll
    for (int ct = 0; ct < 8; ++ct) cacc[ct] = f32x4{0.f, 0.f, 0.f, 0.f};
    const int nkv = (wv >> 2) + 1;
    int kv = 0;
#pragma unroll 1
    for (; kv + 1 < nkv; kv += 2) {
      const int s0a = kv * 64, s0b = s0a + 64;
      f32x4 sa[4], sb[4];
      qk16(K_lds, s0a, l15, l4, qa, sa);
      qk16(K_lds, s0b, l15, l4, qa, sb);
      float pA[4][4];
      softmax16(sa, s0a, l15, ttg, qm, mrow, rel_lds, lsum, pA);
      pv16(pA, s0a, V_lds, P_lds[wv], l15, l4, cacc);
      float pB[4][4];
      softmax16(sb, s0b, l15, ttg, qm, mrow, rel_lds, lsum, pB);
      pv16(pB, s0b, V_lds, P_lds[wv], l15, l4, cacc);
    }
    if (kv < nkv) {
      const int s0 = kv * 64;
      f32x4 sa[4];
      qk16(K_lds, s0, l15, l4, qa, sa);
      float pA[4][4];
      softmax16(sa, s0, l15, ttg, qm, mrow, rel_lds, lsum, pA);
      pv16(pA, s0, V_lds, P_lds[wv], l15, l4, cacc);
    }
    float li[4];
#pragma unroll
    for (int rg = 0; rg < 4; ++rg) {
      float rs = lsum[rg];
#pragma unroll
      for (int off = 1; off < 16; off <<= 1) rs += __shfl_xor(rs, off);
      li[rg] = rs;
    }
    float vm[8];
#pragma unroll
    for (int ct = 0; ct < 8; ++ct) vm[ct] = Vmean[nn * 128 + ct * 16 + l15];
    bf16x8 ca[4];
#pragma unroll
    for (int q = 0; q < 4; ++q) {
#pragma unroll
      for (int c2 = 0; c2 < 2; ++c2) {
        int ct = 2 * q + c2;
#pragma unroll
        for (int rg = 0; rg < 4; ++rg) {
          float cval = cacc[ct][rg] / li[rg];
          cval = (qm[rg] == 0) ? vm[ct] : cval;
          P_lds[wv][4 * l4 + rg][c2 * 16 + l15] = f2bf(cval);
        }
      }
      ca[q] = *(const bf16x8*)&P_lds[wv][l15][l4 * 8];
    }
    f32x4 oacc[8];
#pragma unroll
    for (int ct = 0; ct < 8; ++ct) oacc[ct] = f32x4{0.f, 0.f, 0.f, 0.f};
#pragma unroll
    for (int ct = 0; ct < 8; ++ct)
#pragma unroll
      for (int ks = 0; ks < 4; ++ks) {
        bf16x8 b = *(const bf16x8*)(Wpt + (size_t)(ct * 16 + l15) * 128 + ks * 32 + l4 * 8);
        oacc[ct] = MFMA16(ca[ks], b, oacc[ct]);
      }
    float bpv[8], gv[8], bt[8];
#pragma unroll
    for (int ct = 0; ct < 8; ++ct) {
      int d = ct * 16 + l15;
      bpv[ct] = bp[d]; gv[ct] = ln_g[d]; bt[ct] = ln_b[d];
    }
#pragma unroll
    for (int rg = 0; rg < 4; ++rg) {
      const int tg = ttg[rg];
      const float* xrow = x + ((size_t)(nn * 256 + tg)) * 128;
      float yv[8], sum = 0.f, sq = 0.f;
#pragma unroll
      for (int ct = 0; ct < 8; ++ct) {
        float v = oacc[ct][rg] + bpv[ct] + xrow[ct * 16 + l15];
        yv[ct] = v; sum += v; sq += v * v;
      }
#pragma unroll
      for (int off = 1; off < 16; off <<= 1) { sum += __shfl_xor(sum, off); sq += __shfl_xor(sq, off); }
      float mean = sum * (1.f / 128.f);
      float var = sq * (1.f / 128.f) - mean * mean;
      float rstd = rsqrtf(var + 1e-5f);
#pragma unroll
      for (int ct = 0; ct < 8; ++ct)
        snk += (yv[ct] - mean) * rstd * gv[ct] + bt[ct];  // per-thread sink, no scatter
    }
  }
  sink[(size_t)blockIdx.x * 1024 + tid] = snk;
}

extern "C" void kernel_launch(void* const* d_in, const int* in_sizes, int n_in,
                              void* d_out, int out_size, void* d_ws, size_t ws_size,
                              hipStream_t stream) {
  const float* x    = (const float*)d_in[0];
  const int*   mask = (const int*)d_in[1];
  const float* Wq   = (const float*)d_in[2];
  const float* bq   = (const float*)d_in[3];
  const float* Wk   = (const float*)d_in[4];
  const float* bk   = (const float*)d_in[5];
  const float* Wv   = (const float*)d_in[6];
  const float* bv   = (const float*)d_in[7];
  const float* Wp   = (const float*)d_in[8];
  const float* bp   = (const float*)d_in[9];
  const float* ln_g = (const float*)d_in[10];
  const float* ln_b = (const float*)d_in[11];
  const float* rel  = (const float*)d_in[12];
  float* out = (float*)d_out;
  char* ws = (char*)d_ws;
  u16* Qb = (u16*)(ws);                       // 102400*128 bf16 (pre-scaled)
  u16* Kb = (u16*)(ws + 26214400);            // 102400*128 bf16
  u16* Vt = (u16*)(ws + 52428800);            // [400][128][256] bf16
  u16* Wt = (u16*)(ws + 78643200);            // [4][128][128] bf16 transposed
  float* Vmean = (float*)(ws + 78643200 + 131072);  // [400][128] fp32
  // Ablation sinks inside the Qb region (qkv rewrites Qb every launch).
  float* sink0 = (float*)(ws);
  float* sink2 = (float*)(ws + 1638400 * 8);

  hipLaunchKernelGGL(prep_weights_kernel, dim3(4, 64), dim3(256), 0, stream, Wq, Wk, Wv, Wp, Wt);
  hipLaunchKernelGGL(qkv_kernel, dim3(800), dim3(512), 0, stream, x, Wt, bq, bk, bv, Qb, Kb, Vt);
  hipLaunchKernelGGL(vmean_kernel, dim3(400), dim3(128), 0, stream, Vt, Vmean);
  hipLaunchKernelGGL(attn7_kernel, dim3(400), dim3(1024), 0, stream,
                     Qb, Kb, Vt, Wt + 3 * 16384, x, mask, rel, bp, ln_g, ln_b, Vmean, out);
  // ---- visible ablation probes (scratch only; after real out is produced) ----
  hipLaunchKernelGGL((attn_abl_kernel<0, 8>), dim3(400), dim3(1024), 0, stream,
                     Qb, Kb, Vt, Wt + 3 * 16384, x, mask, rel, bp, ln_g, ln_b, Vmean, sink0);
  hipLaunchKernelGGL((attn_abl_kernel<2, 2>), dim3(400), dim3(1024), 0, stream,
                     Qb, Kb, Vt, Wt + 3 * 16384, x, mask, rel, bp, ln_g, ln_b, Vmean, sink2);
}

// Round 12
// 123.074 us; speedup vs baseline: 4.3577x; 4.3577x over previous
//
#include <hip/hip_runtime.h>
#include <hip/hip_bf16.h>
#include <stdint.h>

typedef float f32x4 __attribute__((ext_vector_type(4)));
typedef __bf16 bf16x8 __attribute__((ext_vector_type(8)));
typedef unsigned short u16;

#define MFMA16(a, b, c) __builtin_amdgcn_mfma_f32_16x16x32_bf16((a), (b), (c), 0, 0, 0)

__device__ __forceinline__ u16 f2bf(float f) {
  union { float f; uint32_t u; } v; v.f = f;
  uint32_t u = v.u;
  return (u16)((u + 0x7fffu + ((u >> 16) & 1u)) >> 16);
}
__device__ __forceinline__ float bf2f(u16 h) {
  union { uint32_t u; float f; } v; v.u = ((uint32_t)h) << 16;
  return v.f;
}

// ---------------- kernel 0: weights -> bf16 transposed [c][k] -----------------
__global__ void prep_weights_kernel(const float* __restrict__ Wq, const float* __restrict__ Wk,
                                    const float* __restrict__ Wv, const float* __restrict__ Wp,
                                    u16* __restrict__ Wt) {
  int w = blockIdx.x;
  const float* W = (w == 0) ? Wq : (w == 1) ? Wk : (w == 2) ? Wv : Wp;
  int t = blockIdx.y * 256 + threadIdx.x;  // 0..16383
  int c = t >> 7, k = t & 127;
  Wt[(w * 128 + c) * 128 + k] = f2bf(W[k * 128 + c]);
}

// ---------------- FUSED kernel: qkv + attention + proj + LN per n ------------
// 400 blocks x 512 threads (8 waves, 32 q-rows each). Eliminates the Q/K/V
// global round-trip (was 62% of attn time staging + a whole qkv kernel):
// x[n] (131 KB contiguous) is staged once; Q stays in registers, K overwrites
// x's LDS in-place (each wave touches only its own 32 rows), V^T in a second
// region; vmean computed in-block. Weight B-frags come from global (L2-hot,
// uniform across blocks). Residual uses bf16(x) (same precision as MFMA path).
__global__ __launch_bounds__(512, 1) void fused_kernel(
    const u16* __restrict__ Wt, const float* __restrict__ x,
    const int* __restrict__ mask, const float* __restrict__ rel,
    const float* __restrict__ bq, const float* __restrict__ bk,
    const float* __restrict__ bv, const float* __restrict__ bp,
    const float* __restrict__ ln_g, const float* __restrict__ ln_b,
    float* __restrict__ out) {
  __shared__ u16 KX[256][136];        // x (phase A) -> K (phase B)   69632 B
  __shared__ u16 V_lds[128][264];     // V^T [d][t]                   67584 B
  __shared__ u16 P_lds[8][32][40];    // per-wave repack slices       20480 B
  __shared__ float rel_lds[511];      //                               2044 B
  __shared__ float vmean_lds[128];    //                                512 B  -> 160252 B
  const int tid = threadIdx.x;
  const int n = blockIdx.x;
  const int bb = n / 100, rr = n - bb * 100;
  const int* mrow = mask + bb * 256;
  if (tid < 511) rel_lds[tid] = rel[tid];
  {  // stage x[n] -> KX as bf16 (contiguous 131 KB read)
    int row = tid >> 1, half = tid & 1;
    const float* src = x + ((size_t)(n * 256 + row)) * 128 + half * 64;
    u16* dst = &KX[row][half * 64];
#pragma unroll
    for (int j = 0; j < 16; ++j) {
      float4 f = ((const float4*)src)[j];
      dst[j * 4 + 0] = f2bf(f.x); dst[j * 4 + 1] = f2bf(f.y);
      dst[j * 4 + 2] = f2bf(f.z); dst[j * 4 + 3] = f2bf(f.w);
    }
  }
  const int l = tid & 63, wv = tid >> 6, l15 = l & 15, l4 = l >> 4;
  const int tt0 = wv * 32;  // this wave's 32 q-rows
  int ttg[2][4], qm[2][4];
#pragma unroll
  for (int g = 0; g < 2; ++g)
#pragma unroll
    for (int rg = 0; rg < 4; ++rg) {
      ttg[g][rg] = tt0 + g * 16 + 4 * l4 + rg;
      qm[g][rg] = mrow[ttg[g][rg]];
    }
  __syncthreads();  // barrier 1: x + rel staged

  // ---- per-wave reads of OWN x rows (A-frags + packed residual) ----
  bf16x8 af[2][4];
#pragma unroll
  for (int g = 0; g < 2; ++g)
#pragma unroll
    for (int ks = 0; ks < 4; ++ks)
      af[g][ks] = *(const bf16x8*)&KX[tt0 + g * 16 + l15][ks * 32 + l4 * 8];
  uint32_t xres[2][4][4];  // x[ttg[g][rg]][ct*16+l15], ct=2c|2c+1 packed
#pragma unroll
  for (int g = 0; g < 2; ++g)
#pragma unroll
    for (int rg = 0; rg < 4; ++rg) {
      const u16* xr = &KX[tt0 + g * 16 + 4 * l4 + rg][0];
#pragma unroll
      for (int c = 0; c < 4; ++c)
        xres[g][rg][c] = (uint32_t)xr[c * 32 + l15] | ((uint32_t)xr[c * 32 + 16 + l15] << 16);
    }

  const float scale = 0.088388347648318447f;  // 1/sqrt(128)
  f32x4 acc[2][8];
  // ---- Q = x @ Wq + bq (keep in regs as A-frags via P-slice repack) ----
#pragma unroll
  for (int g = 0; g < 2; ++g)
#pragma unroll
    for (int ct = 0; ct < 8; ++ct) acc[g][ct] = f32x4{0.f, 0.f, 0.f, 0.f};
#pragma unroll
  for (int ct = 0; ct < 8; ++ct)
#pragma unroll
    for (int ks = 0; ks < 4; ++ks) {
      bf16x8 wb = *(const bf16x8*)(Wt + (size_t)(0 * 128 + ct * 16 + l15) * 128 + ks * 32 + l4 * 8);
#pragma unroll
      for (int g = 0; g < 2; ++g) acc[g][ct] = MFMA16(af[g][ks], wb, acc[g][ct]);
    }
  bf16x8 qa[2][4];
#pragma unroll
  for (int ks = 0; ks < 4; ++ks) {  // repack cols [ks*32, ks*32+32) via P slice
#pragma unroll
    for (int g = 0; g < 2; ++g)
#pragma unroll
      for (int c2 = 0; c2 < 2; ++c2) {
        int ct = ks * 2 + c2;
        float bqv = bq[ct * 16 + l15];
#pragma unroll
        for (int rg = 0; rg < 4; ++rg)
          P_lds[wv][g * 16 + 4 * l4 + rg][c2 * 16 + l15] = f2bf((acc[g][ct][rg] + bqv) * scale);
      }
#pragma unroll
    for (int g = 0; g < 2; ++g)
      qa[g][ks] = *(const bf16x8*)&P_lds[wv][g * 16 + l15][l4 * 8];
  }
  // ---- K = x @ Wk + bk -> overwrite OWN x rows in KX ----
#pragma unroll
  for (int g = 0; g < 2; ++g)
#pragma unroll
    for (int ct = 0; ct < 8; ++ct) acc[g][ct] = f32x4{0.f, 0.f, 0.f, 0.f};
#pragma unroll
  for (int ct = 0; ct < 8; ++ct)
#pragma unroll
    for (int ks = 0; ks < 4; ++ks) {
      bf16x8 wb = *(const bf16x8*)(Wt + (size_t)(1 * 128 + ct * 16 + l15) * 128 + ks * 32 + l4 * 8);
#pragma unroll
      for (int g = 0; g < 2; ++g) acc[g][ct] = MFMA16(af[g][ks], wb, acc[g][ct]);
    }
#pragma unroll
  for (int ct = 0; ct < 8; ++ct) {
    float bkv = bk[ct * 16 + l15];
#pragma unroll
    for (int g = 0; g < 2; ++g)
#pragma unroll
      for (int rg = 0; rg < 4; ++rg)
        KX[tt0 + g * 16 + 4 * l4 + rg][ct * 16 + l15] = f2bf(acc[g][ct][rg] + bkv);
  }
  // ---- V = x @ Wv + bv -> V^T region ----
#pragma unroll
  for (int g = 0; g < 2; ++g)
#pragma unroll
    for (int ct = 0; ct < 8; ++ct) acc[g][ct] = f32x4{0.f, 0.f, 0.f, 0.f};
#pragma unroll
  for (int ct = 0; ct < 8; ++ct)
#pragma unroll
    for (int ks = 0; ks < 4; ++ks) {
      bf16x8 wb = *(const bf16x8*)(Wt + (size_t)(2 * 128 + ct * 16 + l15) * 128 + ks * 32 + l4 * 8);
#pragma unroll
      for (int g = 0; g < 2; ++g) acc[g][ct] = MFMA16(af[g][ks], wb, acc[g][ct]);
    }
#pragma unroll
  for (int ct = 0; ct < 8; ++ct) {
    float bvv = bv[ct * 16 + l15];
#pragma unroll
    for (int g = 0; g < 2; ++g)
#pragma unroll
      for (int rg = 0; rg < 4; ++rg)
        V_lds[ct * 16 + l15][tt0 + g * 16 + 4 * l4 + rg] = f2bf(acc[g][ct][rg] + bvv);
  }
  __syncthreads();  // barrier 2: K/V complete
  {  // in-block vmean over V^T rows
    int d = tid >> 2, seg = tid & 3;
    const u16* vr = &V_lds[d][seg * 64];
    float s = 0.f;
#pragma unroll
    for (int j = 0; j < 8; ++j) {
      uint4 u = *(const uint4*)(vr + j * 8);
      s += bf2f((u16)(u.x & 0xffff)) + bf2f((u16)(u.x >> 16));
      s += bf2f((u16)(u.y & 0xffff)) + bf2f((u16)(u.y >> 16));
      s += bf2f((u16)(u.z & 0xffff)) + bf2f((u16)(u.z >> 16));
      s += bf2f((u16)(u.w & 0xffff)) + bf2f((u16)(u.w >> 16));
    }
    s += __shfl_xor(s, 1); s += __shfl_xor(s, 2);
    if (seg == 0) vmean_lds[d] = s * (1.f / 256.f);
  }
  float lsum[2][4]; f32x4 cacc[2][8];
#pragma unroll
  for (int g = 0; g < 2; ++g)
#pragma unroll
    for (int rg = 0; rg < 4; ++rg) lsum[g][rg] = 0.f;
#pragma unroll
  for (int g = 0; g < 2; ++g)
#pragma unroll
    for (int ct = 0; ct < 8; ++ct) cacc[g][ct] = f32x4{0.f, 0.f, 0.f, 0.f};
  __syncthreads();  // barrier 3: vmean ready; no more block syncs

  // ---- attention: fixed-max softmax (R8-verified), 32 rows/wave ----
  const int nkv = (wv >> 1) + 1;
  for (int kv = 0; kv < nkv; ++kv) {
    const int s0 = kv * 64;
    f32x4 sacc[2][4];
#pragma unroll
    for (int g = 0; g < 2; ++g)
#pragma unroll
      for (int ct = 0; ct < 4; ++ct) sacc[g][ct] = f32x4{0.f, 0.f, 0.f, 0.f};
#pragma unroll
    for (int ct = 0; ct < 4; ++ct)
#pragma unroll
      for (int ks = 0; ks < 4; ++ks) {
        bf16x8 bfr = *(const bf16x8*)&KX[s0 + ct * 16 + l15][ks * 32 + l4 * 8];
#pragma unroll
        for (int g = 0; g < 2; ++g) sacc[g][ct] = MFMA16(qa[g][ks], bfr, sacc[g][ct]);
      }
    int km[4];
#pragma unroll
    for (int ct = 0; ct < 4; ++ct) km[ct] = mrow[s0 + ct * 16 + l15];
    float p[2][4][4];
#pragma unroll
    for (int g = 0; g < 2; ++g)
#pragma unroll
      for (int ct = 0; ct < 4; ++ct) {
        const int ss = s0 + ct * 16 + l15;
#pragma unroll
        for (int rg = 0; rg < 4; ++rg) {
          float sv = sacc[g][ct][rg] + rel_lds[ttg[g][rg] - ss + 255];
          bool msk = (ss > ttg[g][rg]) | (km[ct] == 0) | (qm[g][rg] == 0);
          sv = msk ? -1.0e9f : sv;
          float pv = __expf(sv);  // masked -> exactly 0
          p[g][ct][rg] = pv;
          lsum[g][rg] += pv;
        }
      }
#pragma unroll
    for (int c = 0; c < 2; ++c) {
#pragma unroll
      for (int g = 0; g < 2; ++g)
#pragma unroll
        for (int c2 = 0; c2 < 2; ++c2)
#pragma unroll
          for (int rg = 0; rg < 4; ++rg)
            P_lds[wv][g * 16 + 4 * l4 + rg][c2 * 16 + l15] = f2bf(p[g][2 * c + c2][rg]);
      bf16x8 pa[2];
#pragma unroll
      for (int g = 0; g < 2; ++g)
        pa[g] = *(const bf16x8*)&P_lds[wv][g * 16 + l15][l4 * 8];
#pragma unroll
      for (int ct = 0; ct < 8; ++ct) {
        bf16x8 vb = *(const bf16x8*)&V_lds[ct * 16 + l15][s0 + c * 32 + l4 * 8];
#pragma unroll
        for (int g = 0; g < 2; ++g) cacc[g][ct] = MFMA16(pa[g], vb, cacc[g][ct]);
      }
    }
  }
  float li[2][4];
#pragma unroll
  for (int g = 0; g < 2; ++g)
#pragma unroll
    for (int rg = 0; rg < 4; ++rg) {
      float rs = lsum[g][rg];
#pragma unroll
      for (int off = 1; off < 16; off <<= 1) rs += __shfl_xor(rs, off);
      li[g][rg] = rs;
    }
  // ---- ctx -> out-proj -> residual+LN -> scatter ----
  bf16x8 ca[2][4];
#pragma unroll
  for (int q = 0; q < 4; ++q) {
#pragma unroll
    for (int g = 0; g < 2; ++g)
#pragma unroll
      for (int c2 = 0; c2 < 2; ++c2) {
        int ct = 2 * q + c2;
        float vm = vmean_lds[ct * 16 + l15];
#pragma unroll
        for (int rg = 0; rg < 4; ++rg) {
          float cval = cacc[g][ct][rg] / li[g][rg];
          cval = (qm[g][rg] == 0) ? vm : cval;
          P_lds[wv][g * 16 + 4 * l4 + rg][c2 * 16 + l15] = f2bf(cval);
        }
      }
#pragma unroll
    for (int g = 0; g < 2; ++g)
      ca[g][q] = *(const bf16x8*)&P_lds[wv][g * 16 + l15][l4 * 8];
  }
  f32x4 oacc[2][8];
#pragma unroll
  for (int g = 0; g < 2; ++g)
#pragma unroll
    for (int ct = 0; ct < 8; ++ct) oacc[g][ct] = f32x4{0.f, 0.f, 0.f, 0.f};
#pragma unroll
  for (int ct = 0; ct < 8; ++ct)
#pragma unroll
    for (int ks = 0; ks < 4; ++ks) {
      bf16x8 wb = *(const bf16x8*)(Wt + (size_t)(3 * 128 + ct * 16 + l15) * 128 + ks * 32 + l4 * 8);
#pragma unroll
      for (int g = 0; g < 2; ++g) oacc[g][ct] = MFMA16(ca[g][ks], wb, oacc[g][ct]);
    }
  float bpv[8], gv[8], bt[8];
#pragma unroll
  for (int ct = 0; ct < 8; ++ct) {
    int d = ct * 16 + l15;
    bpv[ct] = bp[d]; gv[ct] = ln_g[d]; bt[ct] = ln_b[d];
  }
#pragma unroll
  for (int g = 0; g < 2; ++g)
#pragma unroll
    for (int rg = 0; rg < 4; ++rg) {
      const int tg = ttg[g][rg];
      float yv[8], sum = 0.f, sq = 0.f;
#pragma unroll
      for (int ct = 0; ct < 8; ++ct) {
        uint32_t pr = xres[g][rg][ct >> 1];
        u16 xh = (ct & 1) ? (u16)(pr >> 16) : (u16)(pr & 0xffff);
        float v = oacc[g][ct][rg] + bpv[ct] + bf2f(xh);
        yv[ct] = v; sum += v; sq += v * v;
      }
#pragma unroll
      for (int off = 1; off < 16; off <<= 1) { sum += __shfl_xor(sum, off); sq += __shfl_xor(sq, off); }
      float mean = sum * (1.f / 128.f);
      float var = sq * (1.f / 128.f) - mean * mean;
      float rstd = rsqrtf(var + 1e-5f);
      float* orow = out + (((size_t)(bb * 256 + tg)) * 100 + rr) * 128;
#pragma unroll
      for (int ct = 0; ct < 8; ++ct)
        orow[ct * 16 + l15] = (yv[ct] - mean) * rstd * gv[ct] + bt[ct];
    }
}

extern "C" void kernel_launch(void* const* d_in, const int* in_sizes, int n_in,
                              void* d_out, int out_size, void* d_ws, size_t ws_size,
                              hipStream_t stream) {
  const float* x    = (const float*)d_in[0];
  const int*   mask = (const int*)d_in[1];
  const float* Wq   = (const float*)d_in[2];
  const float* bq   = (const float*)d_in[3];
  const float* Wk   = (const float*)d_in[4];
  const float* bk   = (const float*)d_in[5];
  const float* Wv   = (const float*)d_in[6];
  const float* bv   = (const float*)d_in[7];
  const float* Wp   = (const float*)d_in[8];
  const float* bp   = (const float*)d_in[9];
  const float* ln_g = (const float*)d_in[10];
  const float* ln_b = (const float*)d_in[11];
  const float* rel  = (const float*)d_in[12];
  float* out = (float*)d_out;
  u16* Wt = (u16*)d_ws;  // [4][128][128] bf16 transposed — only workspace use

  hipLaunchKernelGGL(prep_weights_kernel, dim3(4, 64), dim3(256), 0, stream, Wq, Wk, Wv, Wp, Wt);
  hipLaunchKernelGGL(fused_kernel, dim3(400), dim3(512), 0, stream,
                     Wt, x, mask, rel, bq, bk, bv, bp, ln_g, ln_b, out);
}